// Round 20
// baseline (641.829 us; speedup 1.0000x reference)
//
#include <hip/hip_runtime.h>
#include <hip/hip_fp16.h>
#include <math.h>

#define D 128
#define CSH 11      // src-chunk shift: 2048 nodes/chunk -> 25 chunks at N=50000
#define BSH 7       // dst-bucket shift: 128 nodes/bucket -> 391 buckets
#define NB_MAX 512
#define NKEY 3584   // 512 threads x 7 keys >= 128*25

typedef _Float16 f16;
typedef __attribute__((ext_vector_type(8))) _Float16 f16x8;
typedef __attribute__((ext_vector_type(4))) float f32x4;

// ---------------- preprocessing: two-level binning ----------------

__global__ __launch_bounds__(256) void binA_count(
    const int* __restrict__ dst, int* __restrict__ bucketCount, int E)
{
    __shared__ int hist[NB_MAX];
    int tid = threadIdx.x;
    for (int i = tid; i < NB_MAX; i += 256) hist[i] = 0;
    __syncthreads();
    int base = blockIdx.x * 4096;
    for (int i = tid; i < 4096; i += 256) {
        int e = base + i;
        if (e < E) atomicAdd(&hist[dst[e] >> BSH], 1);
    }
    __syncthreads();
    for (int i = tid; i < NB_MAX; i += 256)
        if (hist[i]) atomicAdd(&bucketCount[i], hist[i]);
}

// parallel scan over NBUC (<512) buckets: one element/thread, shuffle scan
__global__ __launch_bounds__(512) void bucket_scan(
    const int* __restrict__ bucketCount, int* __restrict__ bucketBase,
    int* __restrict__ bucketCursor, int* __restrict__ row_off,
    int NBUC, int E, int N)
{
    __shared__ int wsum[8];
    int tid  = threadIdx.x;
    int lane = tid & 63;
    int wid  = tid >> 6;
    int v = (tid < NBUC) ? bucketCount[tid] : 0;
    int x = v;
    #pragma unroll
    for (int o = 1; o < 64; o <<= 1) { int t = __shfl_up(x, o); if (lane >= o) x += t; }
    if (lane == 63) wsum[wid] = x;
    __syncthreads();
    if (tid < 8) {
        int y = wsum[tid];
        #pragma unroll
        for (int o = 1; o < 8; o <<= 1) { int t = __shfl_up(y, o, 8); if (tid >= o) y += t; }
        wsum[tid] = y;
    }
    __syncthreads();
    int excl = (wid ? wsum[wid - 1] : 0) + x - v;
    if (tid <= NBUC) {
        bucketBase[tid] = excl;           // tid==NBUC -> total (=E)
        if (tid < NBUC) bucketCursor[tid] = excl;
    }
    if (tid == 0) row_off[N] = E;
}

// binned record: x = src | (dst<<16)  [lossless: N<65536], y = f32 ew
__global__ __launch_bounds__(256) void binA_scatter(
    const int* __restrict__ src, const int* __restrict__ dst,
    const float* __restrict__ ew, int* __restrict__ bucketCursor,
    int2* __restrict__ binned, int E)
{
    __shared__ int hist[NB_MAX], off[NB_MAX], cbase[NB_MAX];
    int tid = threadIdx.x;
    for (int i = tid; i < NB_MAX; i += 256) { hist[i] = 0; off[i] = 0; }
    __syncthreads();
    int base = blockIdx.x * 4096;
    for (int i = tid; i < 4096; i += 256) {
        int e = base + i;
        if (e < E) atomicAdd(&hist[dst[e] >> BSH], 1);
    }
    __syncthreads();
    for (int i = tid; i < NB_MAX; i += 256)
        if (hist[i]) cbase[i] = atomicAdd(&bucketCursor[i], hist[i]);
    __syncthreads();
    for (int i = tid; i < 4096; i += 256) {
        int e = base + i;
        if (e < E) {
            int d = dst[e];
            int b = d >> BSH;
            int pos = cbase[b] + atomicAdd(&off[b], 1);
            binned[pos] = make_int2(src[e] | (d << 16), __float_as_int(ew[e]));
        }
    }
}

// Pass B: exact CSR per 128-node bucket (391 blocks x 512 thr, ~29KB LDS).
__global__ __launch_bounds__(512) void binB_kernel(
    const int2* __restrict__ binned, const int* __restrict__ bucketBase,
    int2* __restrict__ edge_s, int* __restrict__ row_off,
    float* __restrict__ sdeg, int N, int nchunk)
{
    __shared__ int hist[NKEY];
    __shared__ int cur[NKEY];
    __shared__ float sdl[128];
    __shared__ int wsum[8];

    int b    = blockIdx.x;
    int tid  = threadIdx.x;
    int ebeg = bucketBase[b], eend = bucketBase[b + 1];
    int node0 = b << BSH;
    int nib   = min(128, N - node0);

    for (int i = tid; i < NKEY; i += 512) hist[i] = 0;
    if (tid < 128) sdl[tid] = 0.f;
    __syncthreads();

    for (int e = ebeg + tid; e < eend; e += 512) {
        int2 ed = binned[e];
        int s  = ed.x & 0xffff;
        int dl = (int)(((unsigned)ed.x) >> 16) - node0;
        int ch = s >> CSH;
        atomicAdd(&hist[dl * nchunk + ch], 1);
        atomicAdd(&sdl[dl], __int_as_float(ed.y));
    }
    __syncthreads();

    int base_i = tid * 7;
    int v[7];
    int tot = 0;
    #pragma unroll
    for (int j = 0; j < 7; ++j) { v[j] = hist[base_i + j]; tot += v[j]; }
    int lane = tid & 63, wid = tid >> 6;
    int x = tot;
    #pragma unroll
    for (int o = 1; o < 64; o <<= 1) { int t = __shfl_up(x, o); if (lane >= o) x += t; }
    if (lane == 63) wsum[wid] = x;
    __syncthreads();
    if (tid < 8) {
        int y = wsum[tid];
        #pragma unroll
        for (int o = 1; o < 8; o <<= 1) { int t = __shfl_up(y, o, 8); if (tid >= o) y += t; }
        wsum[tid] = y;
    }
    __syncthreads();
    int p = (wid ? wsum[wid - 1] : 0) + x - tot;
    #pragma unroll
    for (int j = 0; j < 7; ++j) { cur[base_i + j] = p; p += v[j]; }
    __syncthreads();

    for (int dl = tid; dl < nib; dl += 512) {
        row_off[node0 + dl] = ebeg + cur[dl * nchunk];
        sdeg[node0 + dl]    = sdl[dl];
    }
    __syncthreads();

    for (int e = ebeg + tid; e < eend; e += 512) {
        int2 ed = binned[e];
        int s  = ed.x & 0xffff;
        int dl = (int)(((unsigned)ed.x) >> 16) - node0;
        int ch = s >> CSH;
        int pos = ebeg + atomicAdd(&cur[dl * nchunk + ch], 1);
        edge_s[pos] = make_int2(s, ed.y);
    }
}

// ---------------- W pack: f32 -> fp16 hi/lo in MFMA B-fragment order -----
__global__ __launch_bounds__(256) void pack_kernel(
    const float* __restrict__ W1, const float* __restrict__ W2,
    const float* __restrict__ W3, f16* __restrict__ Wp)
{
    int idx = blockIdx.x * 256 + threadIdx.x;   // 6144 total
    if (idx >= 6144) return;
    int lane = idx & 63;
    int t    = idx >> 6;       // 0..95
    int ks   = t & 3;
    int mot  = t >> 2;         // 0..23
    int m    = mot >> 3;
    int ot   = mot & 7;
    const float* W = (m == 0) ? W1 : (m == 1) ? W2 : W3;
    int o  = ot * 16 + (lane & 15);
    int kb = ks * 32 + (lane >> 4) * 8;
    f16x8 hi, lo;
    #pragma unroll
    for (int j = 0; j < 8; ++j) {
        float v = W[(size_t)o * D + kb + j];
        f16 hh = (f16)v;
        hi[j] = hh;
        lo[j] = (f16)(v - (float)hh);
    }
    size_t base = (size_t)ks * 24576 + (size_t)mot * 1024 + (size_t)lane * 8;
    *(f16x8*)&Wp[base]       = hi;
    *(f16x8*)&Wp[base + 512] = lo;
}

// ---------------- MFMA fused 3-matmul, W in registers --------------------
// Each wave owns ONE out-tile (ot = (blockIdx&1)*4 + wid) x 3 matrices:
// 96 VGPR of W frags -> 3 blocks/CU (launch_bounds 256,3). Even/odd block
// pairs cover the same node-tiles (A re-read absorbed by L3).

__global__ __launch_bounds__(256, 3) void gemm_kernel(
    const float* __restrict__ in, const f16* __restrict__ Wp,
    const float* __restrict__ b1, const float* __restrict__ b3,
    const float* __restrict__ sdeg, float* __restrict__ aF,
    float* __restrict__ base_out, int N, int ntiles, int gridb)
{
    int tid  = threadIdx.x;
    int lane = tid & 63;
    int wid  = tid >> 6;
    int col  = lane & 15;
    int g    = lane >> 4;
    int ot   = (blockIdx.x & 1) * 4 + wid;   // out-tile 0..7

    // W fragments: [m][ks][hi/lo]  (one out-tile per wave)
    f16x8 w[3][4][2];
    #pragma unroll
    for (int m = 0; m < 3; ++m) {
        int mot = m * 8 + ot;
        #pragma unroll
        for (int ks = 0; ks < 4; ++ks) {
            const f16* p = Wp + (size_t)ks * 24576 + (size_t)mot * 1024 + (size_t)lane * 8;
            w[m][ks][0] = *(const f16x8*)p;
            w[m][ks][1] = *(const f16x8*)(p + 512);
        }
    }

    int o   = ot * 16 + col;
    float bi1 = b1[o];
    float bi3 = b3[o];

    for (int t = blockIdx.x >> 1; t < ntiles; t += (gridb >> 1)) {
        int n0   = t * 16;
        int nrow = n0 + col;

        f32x4 acc[3];
        #pragma unroll
        for (int m = 0; m < 3; ++m) acc[m] = (f32x4){0.f, 0.f, 0.f, 0.f};

        #pragma unroll
        for (int ks = 0; ks < 4; ++ks) {
            float av[8];
            if (nrow < N) {
                float4 a0 = *(const float4*)&in[(size_t)nrow * D + ks * 32 + g * 8];
                float4 a1 = *(const float4*)&in[(size_t)nrow * D + ks * 32 + g * 8 + 4];
                av[0] = a0.x; av[1] = a0.y; av[2] = a0.z; av[3] = a0.w;
                av[4] = a1.x; av[5] = a1.y; av[6] = a1.z; av[7] = a1.w;
            } else {
                #pragma unroll
                for (int j = 0; j < 8; ++j) av[j] = 0.f;
            }
            f16x8 ahi, alo;
            #pragma unroll
            for (int j = 0; j < 8; ++j) {
                f16 hh = (f16)av[j];
                ahi[j] = hh;
                alo[j] = (f16)(av[j] - (float)hh);
            }
            #pragma unroll
            for (int m = 0; m < 3; ++m) {
                acc[m] = __builtin_amdgcn_mfma_f32_16x16x32_f16(ahi, w[m][ks][0], acc[m], 0, 0, 0);
                acc[m] = __builtin_amdgcn_mfma_f32_16x16x32_f16(alo, w[m][ks][0], acc[m], 0, 0, 0);
                acc[m] = __builtin_amdgcn_mfma_f32_16x16x32_f16(ahi, w[m][ks][1], acc[m], 0, 0, 0);
            }
        }

        #pragma unroll
        for (int r = 0; r < 4; ++r) {
            int node = n0 + g * 4 + r;
            if (node < N) {
                float sv   = sdeg[node];
                float aval = acc[0][r] + bi1;
                float bval = acc[2][r] + bi3 - sv * acc[1][r];
                aF[(size_t)node * D + o]       = aval;
                base_out[(size_t)node * D + o] = bval;
            }
        }
    }
}

// ---------------- CSR aggregate + activation --------------------------
// One wave per node; each HALF-WAVE (32 lanes x float4 = full 512B row)
// handles one edge; 8 edges per half-wave in flight per iteration.

__global__ __launch_bounds__(256) void agg_kernel(
    const float* __restrict__ aF, const float* __restrict__ base,
    const int* __restrict__ row_off, const int2* __restrict__ edge_s,
    float* __restrict__ out, int N, int last)
{
    int lane = threadIdx.x & 63;
    int wid  = threadIdx.x >> 6;
    int node = blockIdx.x * 4 + wid;
    if (node >= N) return;
    int half = lane >> 5;
    int fl   = (lane & 31) * 4;

    float4 acc = make_float4(0.f, 0.f, 0.f, 0.f);
    int beg = row_off[node], end = row_off[node + 1];

    int e = beg + half;
    for (; e + 14 < end; e += 16) {        // 8 edges per half-wave per iter
        int2 m[8];
        #pragma unroll
        for (int i = 0; i < 8; ++i) m[i] = edge_s[e + i * 2];
        float4 v[8];
        #pragma unroll
        for (int i = 0; i < 8; ++i)
            v[i] = *(const float4*)&aF[(size_t)m[i].x * D + fl];
        #pragma unroll
        for (int i = 0; i < 8; ++i) {
            float wgt = __int_as_float(m[i].y);
            acc.x = fmaf(wgt, v[i].x, acc.x);
            acc.y = fmaf(wgt, v[i].y, acc.y);
            acc.z = fmaf(wgt, v[i].z, acc.z);
            acc.w = fmaf(wgt, v[i].w, acc.w);
        }
    }
    for (; e + 6 < end; e += 8) {          // 4-deep
        int2 m[4];
        #pragma unroll
        for (int i = 0; i < 4; ++i) m[i] = edge_s[e + i * 2];
        float4 v[4];
        #pragma unroll
        for (int i = 0; i < 4; ++i)
            v[i] = *(const float4*)&aF[(size_t)m[i].x * D + fl];
        #pragma unroll
        for (int i = 0; i < 4; ++i) {
            float wgt = __int_as_float(m[i].y);
            acc.x = fmaf(wgt, v[i].x, acc.x);
            acc.y = fmaf(wgt, v[i].y, acc.y);
            acc.z = fmaf(wgt, v[i].z, acc.z);
            acc.w = fmaf(wgt, v[i].w, acc.w);
        }
    }
    for (; e < end; e += 2) {
        int2 m = edge_s[e];
        float4 v = *(const float4*)&aF[(size_t)m.x * D + fl];
        float wgt = __int_as_float(m.y);
        acc.x = fmaf(wgt, v.x, acc.x);
        acc.y = fmaf(wgt, v.y, acc.y);
        acc.z = fmaf(wgt, v.z, acc.z);
        acc.w = fmaf(wgt, v.w, acc.w);
    }

    acc.x += __shfl_xor(acc.x, 32);
    acc.y += __shfl_xor(acc.y, 32);
    acc.z += __shfl_xor(acc.z, 32);
    acc.w += __shfl_xor(acc.w, 32);

    if (half == 0) {
        float4 b = *(const float4*)&base[(size_t)node * D + fl];
        float r0 = acc.x + b.x, r1 = acc.y + b.y;
        float r2 = acc.z + b.z, r3 = acc.w + b.w;
        r0 = r0 >= 0.f ? r0 : 0.1f * r0;
        r1 = r1 >= 0.f ? r1 : 0.1f * r1;
        r2 = r2 >= 0.f ? r2 : 0.1f * r2;
        r3 = r3 >= 0.f ? r3 : 0.1f * r3;
        if (last) {
            r0 = 1.f / (1.f + __expf(-r0));
            r1 = 1.f / (1.f + __expf(-r1));
            r2 = 1.f / (1.f + __expf(-r2));
            r3 = 1.f / (1.f + __expf(-r3));
        }
        *(float4*)&out[(size_t)node * D + fl] = make_float4(r0, r1, r2, r3);
    }
}

// ---------------- launch ----------------

extern "C" void kernel_launch(void* const* d_in, const int* in_sizes, int n_in,
                              void* d_out, int out_size, void* d_ws, size_t ws_size,
                              hipStream_t stream) {
    const float* x   = (const float*)d_in[0];
    const int*   ei  = (const int*)d_in[1];
    const float* ew  = (const float*)d_in[2];
    const float* iW1 = (const float*)d_in[3];
    const float* ib1 = (const float*)d_in[4];
    const float* iW2 = (const float*)d_in[5];
    const float* iW3 = (const float*)d_in[6];
    const float* ib3 = (const float*)d_in[7];
    const float* mW1 = (const float*)d_in[8];
    const float* mb1 = (const float*)d_in[9];
    const float* mW2 = (const float*)d_in[10];
    const float* mW3 = (const float*)d_in[11];
    const float* mb3 = (const float*)d_in[12];
    const float* oW1 = (const float*)d_in[13];
    const float* ob1 = (const float*)d_in[14];
    const float* oW2 = (const float*)d_in[15];
    const float* oW3 = (const float*)d_in[16];
    const float* ob3 = (const float*)d_in[17];

    int N = in_sizes[0] / D;
    int E = in_sizes[2];
    const int* src = ei;
    const int* dst = ei + E;
    int nchunk = (N + (1 << CSH) - 1) >> CSH;   // 25
    int NBUC   = (N + (1 << BSH) - 1) >> BSH;   // 391

    char* wsp = (char*)d_ws;
    size_t off = 0;
    auto alloc = [&](size_t bytes) -> void* {
        void* p = wsp + off;
        off += (bytes + 255) & ~(size_t)255;
        return p;
    };
    float* h       = (float*)alloc((size_t)N * D * 4);   // aliased by binned
    float* base    = (float*)alloc((size_t)N * D * 4);
    float* aF      = (float*)alloc((size_t)N * D * 4);
    float* sdeg    = (float*)alloc((size_t)N * 4);
    int*   row_off = (int*)alloc((size_t)(N + 1) * 4);
    int2*  edge_s  = (int2*)alloc((size_t)E * 8);
    int*   bucketCount  = (int*)alloc((size_t)(NBUC + 1) * 4);
    int*   bucketBase   = (int*)alloc((size_t)(NBUC + 1) * 4);
    int*   bucketCursor = (int*)alloc((size_t)(NBUC + 1) * 4);
    f16*   Wp       = (f16*)alloc((size_t)3 * 98304 * 2);

    int2* binned = (int2*)h;   // E*8B = 12.8MB <= h (25.6MB); dead before h's first write

    hipMemsetAsync(bucketCount, 0, (size_t)(NBUC + 1) * 4, stream);

    int ablocks  = (N + 3) / 4;
    int ntiles   = (N + 15) / 16;
    int gridb    = 1536;          // 768 even + 768 odd half-blocks, 3/CU
    int abblocks = (E + 4095) / 4096;

    pack_kernel<<<24, 256, 0, stream>>>(iW1, iW2, iW3, Wp);
    pack_kernel<<<24, 256, 0, stream>>>(mW1, mW2, mW3, Wp + 98304);
    pack_kernel<<<24, 256, 0, stream>>>(oW1, oW2, oW3, Wp + 2 * 98304);

    binA_count<<<abblocks, 256, 0, stream>>>(dst, bucketCount, E);
    bucket_scan<<<1, 512, 0, stream>>>(bucketCount, bucketBase, bucketCursor,
                                       row_off, NBUC, E, N);
    binA_scatter<<<abblocks, 256, 0, stream>>>(src, dst, ew, bucketCursor,
                                               binned, E);
    binB_kernel<<<NBUC, 512, 0, stream>>>(binned, bucketBase, edge_s,
                                          row_off, sdeg, N, nchunk);

    // layer 1 (in): reads x
    gemm_kernel<<<gridb, 256, 0, stream>>>(x, Wp, ib1, ib3, sdeg, aF, base, N, ntiles, gridb);
    agg_kernel<<<ablocks, 256, 0, stream>>>(aF, base, row_off, edge_s, h, N, 0);
    // layers 2..3 (mid, shared weights)
    for (int l = 0; l < 2; ++l) {
        gemm_kernel<<<gridb, 256, 0, stream>>>(h, Wp + 98304, mb1, mb3, sdeg, aF, base, N, ntiles, gridb);
        agg_kernel<<<ablocks, 256, 0, stream>>>(aF, base, row_off, edge_s, h, N, 0);
    }
    // layer 4 (out) -> d_out with sigmoid
    gemm_kernel<<<gridb, 256, 0, stream>>>(h, Wp + 2 * 98304, ob1, ob3, sdeg, aF, base, N, ntiles, gridb);
    agg_kernel<<<ablocks, 256, 0, stream>>>(aF, base, row_off, edge_s, (float*)d_out, N, 1);
}

// Round 21
// 629.757 us; speedup vs baseline: 1.0192x; 1.0192x over previous
//
#include <hip/hip_runtime.h>
#include <hip/hip_fp16.h>
#include <math.h>

#define D 128
#define CSH 11      // src-chunk shift: 2048 nodes/chunk -> 25 chunks at N=50000
#define BSH 7       // dst-bucket shift: 128 nodes/bucket -> 391 buckets
#define NB_MAX 512
#define NKEY 3584   // 512 threads x 7 keys >= 128*25

typedef _Float16 f16;
typedef __attribute__((ext_vector_type(8))) _Float16 f16x8;
typedef __attribute__((ext_vector_type(4))) float f32x4;

// ---------------- preprocessing: two-level binning ----------------

__global__ __launch_bounds__(256) void binA_count(
    const int* __restrict__ dst, int* __restrict__ bucketCount, int E)
{
    __shared__ int hist[NB_MAX];
    int tid = threadIdx.x;
    for (int i = tid; i < NB_MAX; i += 256) hist[i] = 0;
    __syncthreads();
    int base = blockIdx.x * 4096;
    for (int i = tid; i < 4096; i += 256) {
        int e = base + i;
        if (e < E) atomicAdd(&hist[dst[e] >> BSH], 1);
    }
    __syncthreads();
    for (int i = tid; i < NB_MAX; i += 256)
        if (hist[i]) atomicAdd(&bucketCount[i], hist[i]);
}

// parallel scan over NBUC (<512) buckets: one element/thread, shuffle scan
__global__ __launch_bounds__(512) void bucket_scan(
    const int* __restrict__ bucketCount, int* __restrict__ bucketBase,
    int* __restrict__ bucketCursor, int* __restrict__ row_off,
    int NBUC, int E, int N)
{
    __shared__ int wsum[8];
    int tid  = threadIdx.x;
    int lane = tid & 63;
    int wid  = tid >> 6;
    int v = (tid < NBUC) ? bucketCount[tid] : 0;
    int x = v;
    #pragma unroll
    for (int o = 1; o < 64; o <<= 1) { int t = __shfl_up(x, o); if (lane >= o) x += t; }
    if (lane == 63) wsum[wid] = x;
    __syncthreads();
    if (tid < 8) {
        int y = wsum[tid];
        #pragma unroll
        for (int o = 1; o < 8; o <<= 1) { int t = __shfl_up(y, o, 8); if (tid >= o) y += t; }
        wsum[tid] = y;
    }
    __syncthreads();
    int excl = (wid ? wsum[wid - 1] : 0) + x - v;
    if (tid <= NBUC) {
        bucketBase[tid] = excl;           // tid==NBUC -> total (=E)
        if (tid < NBUC) bucketCursor[tid] = excl;
    }
    if (tid == 0) row_off[N] = E;
}

// binned record: x = src | (dst<<16)  [lossless: N<65536], y = f32 ew
__global__ __launch_bounds__(256) void binA_scatter(
    const int* __restrict__ src, const int* __restrict__ dst,
    const float* __restrict__ ew, int* __restrict__ bucketCursor,
    int2* __restrict__ binned, int E)
{
    __shared__ int hist[NB_MAX], off[NB_MAX], cbase[NB_MAX];
    int tid = threadIdx.x;
    for (int i = tid; i < NB_MAX; i += 256) { hist[i] = 0; off[i] = 0; }
    __syncthreads();
    int base = blockIdx.x * 4096;
    for (int i = tid; i < 4096; i += 256) {
        int e = base + i;
        if (e < E) atomicAdd(&hist[dst[e] >> BSH], 1);
    }
    __syncthreads();
    for (int i = tid; i < NB_MAX; i += 256)
        if (hist[i]) cbase[i] = atomicAdd(&bucketCursor[i], hist[i]);
    __syncthreads();
    for (int i = tid; i < 4096; i += 256) {
        int e = base + i;
        if (e < E) {
            int d = dst[e];
            int b = d >> BSH;
            int pos = cbase[b] + atomicAdd(&off[b], 1);
            binned[pos] = make_int2(src[e] | (d << 16), __float_as_int(ew[e]));
        }
    }
}

// Pass B: exact CSR per 128-node bucket (391 blocks x 512 thr, ~29KB LDS).
__global__ __launch_bounds__(512) void binB_kernel(
    const int2* __restrict__ binned, const int* __restrict__ bucketBase,
    int2* __restrict__ edge_s, int* __restrict__ row_off,
    float* __restrict__ sdeg, int N, int nchunk)
{
    __shared__ int hist[NKEY];
    __shared__ int cur[NKEY];
    __shared__ float sdl[128];
    __shared__ int wsum[8];

    int b    = blockIdx.x;
    int tid  = threadIdx.x;
    int ebeg = bucketBase[b], eend = bucketBase[b + 1];
    int node0 = b << BSH;
    int nib   = min(128, N - node0);

    for (int i = tid; i < NKEY; i += 512) hist[i] = 0;
    if (tid < 128) sdl[tid] = 0.f;
    __syncthreads();

    for (int e = ebeg + tid; e < eend; e += 512) {
        int2 ed = binned[e];
        int s  = ed.x & 0xffff;
        int dl = (int)(((unsigned)ed.x) >> 16) - node0;
        int ch = s >> CSH;
        atomicAdd(&hist[dl * nchunk + ch], 1);
        atomicAdd(&sdl[dl], __int_as_float(ed.y));
    }
    __syncthreads();

    int base_i = tid * 7;
    int v[7];
    int tot = 0;
    #pragma unroll
    for (int j = 0; j < 7; ++j) { v[j] = hist[base_i + j]; tot += v[j]; }
    int lane = tid & 63, wid = tid >> 6;
    int x = tot;
    #pragma unroll
    for (int o = 1; o < 64; o <<= 1) { int t = __shfl_up(x, o); if (lane >= o) x += t; }
    if (lane == 63) wsum[wid] = x;
    __syncthreads();
    if (tid < 8) {
        int y = wsum[tid];
        #pragma unroll
        for (int o = 1; o < 8; o <<= 1) { int t = __shfl_up(y, o, 8); if (tid >= o) y += t; }
        wsum[tid] = y;
    }
    __syncthreads();
    int p = (wid ? wsum[wid - 1] : 0) + x - tot;
    #pragma unroll
    for (int j = 0; j < 7; ++j) { cur[base_i + j] = p; p += v[j]; }
    __syncthreads();

    for (int dl = tid; dl < nib; dl += 512) {
        row_off[node0 + dl] = ebeg + cur[dl * nchunk];
        sdeg[node0 + dl]    = sdl[dl];
    }
    __syncthreads();

    for (int e = ebeg + tid; e < eend; e += 512) {
        int2 ed = binned[e];
        int s  = ed.x & 0xffff;
        int dl = (int)(((unsigned)ed.x) >> 16) - node0;
        int ch = s >> CSH;
        int pos = ebeg + atomicAdd(&cur[dl * nchunk + ch], 1);
        edge_s[pos] = make_int2(s, ed.y);
    }
}

// ---------------- W pack: f32 -> fp16 hi/lo in MFMA B-fragment order -----
__global__ __launch_bounds__(256) void pack_kernel(
    const float* __restrict__ W1, const float* __restrict__ W2,
    const float* __restrict__ W3, f16* __restrict__ Wp)
{
    int idx = blockIdx.x * 256 + threadIdx.x;   // 6144 total
    if (idx >= 6144) return;
    int lane = idx & 63;
    int t    = idx >> 6;       // 0..95
    int ks   = t & 3;
    int mot  = t >> 2;         // 0..23
    int m    = mot >> 3;
    int ot   = mot & 7;
    const float* W = (m == 0) ? W1 : (m == 1) ? W2 : W3;
    int o  = ot * 16 + (lane & 15);
    int kb = ks * 32 + (lane >> 4) * 8;
    f16x8 hi, lo;
    #pragma unroll
    for (int j = 0; j < 8; ++j) {
        float v = W[(size_t)o * D + kb + j];
        f16 hh = (f16)v;
        hi[j] = hh;
        lo[j] = (f16)(v - (float)hh);
    }
    size_t base = (size_t)ks * 24576 + (size_t)mot * 1024 + (size_t)lane * 8;
    *(f16x8*)&Wp[base]       = hi;
    *(f16x8*)&Wp[base + 512] = lo;
}

// ---------------- MFMA fused 3-matmul, W in registers --------------------

__global__ __launch_bounds__(256, 2) void gemm_kernel(
    const float* __restrict__ in, const f16* __restrict__ Wp,
    const float* __restrict__ b1, const float* __restrict__ b3,
    const float* __restrict__ sdeg, float* __restrict__ aF,
    float* __restrict__ base_out, int N, int ntiles, int gridb)
{
    int tid  = threadIdx.x;
    int lane = tid & 63;
    int wid  = tid >> 6;
    int col  = lane & 15;
    int g    = lane >> 4;

    f16x8 w[3][2][4][2];
    #pragma unroll
    for (int m = 0; m < 3; ++m)
        #pragma unroll
        for (int oti = 0; oti < 2; ++oti) {
            int mot = m * 8 + wid * 2 + oti;
            #pragma unroll
            for (int ks = 0; ks < 4; ++ks) {
                const f16* p = Wp + (size_t)ks * 24576 + (size_t)mot * 1024 + (size_t)lane * 8;
                w[m][oti][ks][0] = *(const f16x8*)p;
                w[m][oti][ks][1] = *(const f16x8*)(p + 512);
            }
        }

    float bi1[2], bi3[2];
    #pragma unroll
    for (int oti = 0; oti < 2; ++oti) {
        int o = (wid * 2 + oti) * 16 + col;
        bi1[oti] = b1[o];
        bi3[oti] = b3[o];
    }

    for (int t = blockIdx.x; t < ntiles; t += gridb) {
        int n0   = t * 16;
        int nrow = n0 + col;

        f32x4 acc[3][2];
        #pragma unroll
        for (int m = 0; m < 3; ++m)
            #pragma unroll
            for (int oti = 0; oti < 2; ++oti)
                acc[m][oti] = (f32x4){0.f, 0.f, 0.f, 0.f};

        #pragma unroll
        for (int ks = 0; ks < 4; ++ks) {
            float av[8];
            if (nrow < N) {
                float4 a0 = *(const float4*)&in[(size_t)nrow * D + ks * 32 + g * 8];
                float4 a1 = *(const float4*)&in[(size_t)nrow * D + ks * 32 + g * 8 + 4];
                av[0] = a0.x; av[1] = a0.y; av[2] = a0.z; av[3] = a0.w;
                av[4] = a1.x; av[5] = a1.y; av[6] = a1.z; av[7] = a1.w;
            } else {
                #pragma unroll
                for (int j = 0; j < 8; ++j) av[j] = 0.f;
            }
            f16x8 ahi, alo;
            #pragma unroll
            for (int j = 0; j < 8; ++j) {
                f16 hh = (f16)av[j];
                ahi[j] = hh;
                alo[j] = (f16)(av[j] - (float)hh);
            }
            #pragma unroll
            for (int m = 0; m < 3; ++m)
                #pragma unroll
                for (int oti = 0; oti < 2; ++oti) {
                    acc[m][oti] = __builtin_amdgcn_mfma_f32_16x16x32_f16(ahi, w[m][oti][ks][0], acc[m][oti], 0, 0, 0);
                    acc[m][oti] = __builtin_amdgcn_mfma_f32_16x16x32_f16(alo, w[m][oti][ks][0], acc[m][oti], 0, 0, 0);
                    acc[m][oti] = __builtin_amdgcn_mfma_f32_16x16x32_f16(ahi, w[m][oti][ks][1], acc[m][oti], 0, 0, 0);
                }
        }

        #pragma unroll
        for (int oti = 0; oti < 2; ++oti) {
            int o = (wid * 2 + oti) * 16 + col;
            #pragma unroll
            for (int r = 0; r < 4; ++r) {
                int node = n0 + g * 4 + r;
                if (node < N) {
                    float sv   = sdeg[node];
                    float aval = acc[0][oti][r] + bi1[oti];
                    float bval = acc[2][oti][r] + bi3[oti] - sv * acc[1][oti][r];
                    aF[(size_t)node * D + o]       = aval;
                    base_out[(size_t)node * D + o] = bval;
                }
            }
        }
    }
}

// ---------------- CSR aggregate + activation --------------------------
// One wave per node; each HALF-WAVE (32 lanes x float4 = full 512B row)
// handles one edge; 8 edges per half-wave in flight per iteration.

__global__ __launch_bounds__(256) void agg_kernel(
    const float* __restrict__ aF, const float* __restrict__ base,
    const int* __restrict__ row_off, const int2* __restrict__ edge_s,
    float* __restrict__ out, int N, int last)
{
    int lane = threadIdx.x & 63;
    int wid  = threadIdx.x >> 6;
    int node = blockIdx.x * 4 + wid;
    if (node >= N) return;
    int half = lane >> 5;
    int fl   = (lane & 31) * 4;

    float4 acc = make_float4(0.f, 0.f, 0.f, 0.f);
    int beg = row_off[node], end = row_off[node + 1];

    int e = beg + half;
    for (; e + 14 < end; e += 16) {        // 8 edges per half-wave per iter
        int2 m[8];
        #pragma unroll
        for (int i = 0; i < 8; ++i) m[i] = edge_s[e + i * 2];
        float4 v[8];
        #pragma unroll
        for (int i = 0; i < 8; ++i)
            v[i] = *(const float4*)&aF[(size_t)m[i].x * D + fl];
        #pragma unroll
        for (int i = 0; i < 8; ++i) {
            float wgt = __int_as_float(m[i].y);
            acc.x = fmaf(wgt, v[i].x, acc.x);
            acc.y = fmaf(wgt, v[i].y, acc.y);
            acc.z = fmaf(wgt, v[i].z, acc.z);
            acc.w = fmaf(wgt, v[i].w, acc.w);
        }
    }
    for (; e + 6 < end; e += 8) {          // 4-deep
        int2 m[4];
        #pragma unroll
        for (int i = 0; i < 4; ++i) m[i] = edge_s[e + i * 2];
        float4 v[4];
        #pragma unroll
        for (int i = 0; i < 4; ++i)
            v[i] = *(const float4*)&aF[(size_t)m[i].x * D + fl];
        #pragma unroll
        for (int i = 0; i < 4; ++i) {
            float wgt = __int_as_float(m[i].y);
            acc.x = fmaf(wgt, v[i].x, acc.x);
            acc.y = fmaf(wgt, v[i].y, acc.y);
            acc.z = fmaf(wgt, v[i].z, acc.z);
            acc.w = fmaf(wgt, v[i].w, acc.w);
        }
    }
    for (; e < end; e += 2) {
        int2 m = edge_s[e];
        float4 v = *(const float4*)&aF[(size_t)m.x * D + fl];
        float wgt = __int_as_float(m.y);
        acc.x = fmaf(wgt, v.x, acc.x);
        acc.y = fmaf(wgt, v.y, acc.y);
        acc.z = fmaf(wgt, v.z, acc.z);
        acc.w = fmaf(wgt, v.w, acc.w);
    }

    acc.x += __shfl_xor(acc.x, 32);
    acc.y += __shfl_xor(acc.y, 32);
    acc.z += __shfl_xor(acc.z, 32);
    acc.w += __shfl_xor(acc.w, 32);

    if (half == 0) {
        float4 b = *(const float4*)&base[(size_t)node * D + fl];
        float r0 = acc.x + b.x, r1 = acc.y + b.y;
        float r2 = acc.z + b.z, r3 = acc.w + b.w;
        r0 = r0 >= 0.f ? r0 : 0.1f * r0;
        r1 = r1 >= 0.f ? r1 : 0.1f * r1;
        r2 = r2 >= 0.f ? r2 : 0.1f * r2;
        r3 = r3 >= 0.f ? r3 : 0.1f * r3;
        if (last) {
            r0 = 1.f / (1.f + __expf(-r0));
            r1 = 1.f / (1.f + __expf(-r1));
            r2 = 1.f / (1.f + __expf(-r2));
            r3 = 1.f / (1.f + __expf(-r3));
        }
        *(float4*)&out[(size_t)node * D + fl] = make_float4(r0, r1, r2, r3);
    }
}

// ---------------- launch ----------------

extern "C" void kernel_launch(void* const* d_in, const int* in_sizes, int n_in,
                              void* d_out, int out_size, void* d_ws, size_t ws_size,
                              hipStream_t stream) {
    const float* x   = (const float*)d_in[0];
    const int*   ei  = (const int*)d_in[1];
    const float* ew  = (const float*)d_in[2];
    const float* iW1 = (const float*)d_in[3];
    const float* ib1 = (const float*)d_in[4];
    const float* iW2 = (const float*)d_in[5];
    const float* iW3 = (const float*)d_in[6];
    const float* ib3 = (const float*)d_in[7];
    const float* mW1 = (const float*)d_in[8];
    const float* mb1 = (const float*)d_in[9];
    const float* mW2 = (const float*)d_in[10];
    const float* mW3 = (const float*)d_in[11];
    const float* mb3 = (const float*)d_in[12];
    const float* oW1 = (const float*)d_in[13];
    const float* ob1 = (const float*)d_in[14];
    const float* oW2 = (const float*)d_in[15];
    const float* oW3 = (const float*)d_in[16];
    const float* ob3 = (const float*)d_in[17];

    int N = in_sizes[0] / D;
    int E = in_sizes[2];
    const int* src = ei;
    const int* dst = ei + E;
    int nchunk = (N + (1 << CSH) - 1) >> CSH;   // 25
    int NBUC   = (N + (1 << BSH) - 1) >> BSH;   // 391

    char* wsp = (char*)d_ws;
    size_t off = 0;
    auto alloc = [&](size_t bytes) -> void* {
        void* p = wsp + off;
        off += (bytes + 255) & ~(size_t)255;
        return p;
    };
    float* h       = (float*)alloc((size_t)N * D * 4);   // aliased by binned
    float* base    = (float*)alloc((size_t)N * D * 4);
    float* aF      = (float*)alloc((size_t)N * D * 4);
    float* sdeg    = (float*)alloc((size_t)N * 4);
    int*   row_off = (int*)alloc((size_t)(N + 1) * 4);
    int2*  edge_s  = (int2*)alloc((size_t)E * 8);
    int*   bucketCount  = (int*)alloc((size_t)(NBUC + 1) * 4);
    int*   bucketBase   = (int*)alloc((size_t)(NBUC + 1) * 4);
    int*   bucketCursor = (int*)alloc((size_t)(NBUC + 1) * 4);
    f16*   Wp       = (f16*)alloc((size_t)3 * 98304 * 2);

    int2* binned = (int2*)h;   // E*8B = 12.8MB <= h (25.6MB); dead before h's first write

    hipMemsetAsync(bucketCount, 0, (size_t)(NBUC + 1) * 4, stream);

    int ablocks  = (N + 3) / 4;
    int ntiles   = (N + 15) / 16;
    int gridb    = 512;
    int abblocks = (E + 4095) / 4096;

    pack_kernel<<<24, 256, 0, stream>>>(iW1, iW2, iW3, Wp);
    pack_kernel<<<24, 256, 0, stream>>>(mW1, mW2, mW3, Wp + 98304);
    pack_kernel<<<24, 256, 0, stream>>>(oW1, oW2, oW3, Wp + 2 * 98304);

    binA_count<<<abblocks, 256, 0, stream>>>(dst, bucketCount, E);
    bucket_scan<<<1, 512, 0, stream>>>(bucketCount, bucketBase, bucketCursor,
                                       row_off, NBUC, E, N);
    binA_scatter<<<abblocks, 256, 0, stream>>>(src, dst, ew, bucketCursor,
                                               binned, E);
    binB_kernel<<<NBUC, 512, 0, stream>>>(binned, bucketBase, edge_s,
                                          row_off, sdeg, N, nchunk);

    // layer 1 (in): reads x
    gemm_kernel<<<gridb, 256, 0, stream>>>(x, Wp, ib1, ib3, sdeg, aF, base, N, ntiles, gridb);
    agg_kernel<<<ablocks, 256, 0, stream>>>(aF, base, row_off, edge_s, h, N, 0);
    // layers 2..3 (mid, shared weights)
    for (int l = 0; l < 2; ++l) {
        gemm_kernel<<<gridb, 256, 0, stream>>>(h, Wp + 98304, mb1, mb3, sdeg, aF, base, N, ntiles, gridb);
        agg_kernel<<<ablocks, 256, 0, stream>>>(aF, base, row_off, edge_s, h, N, 0);
    }
    // layer 4 (out) -> d_out with sigmoid
    gemm_kernel<<<gridb, 256, 0, stream>>>(h, Wp + 2 * 98304, ob1, ob3, sdeg, aF, base, N, ntiles, gridb);
    agg_kernel<<<ablocks, 256, 0, stream>>>(aF, base, row_off, edge_s, (float*)d_out, N, 1);
}